// Round 7
// baseline (650.512 us; speedup 1.0000x reference)
//
#include <hip/hip_runtime.h>
#include <hip/hip_bf16.h>

using u16 = unsigned short;
typedef __bf16 bf16x8 __attribute__((ext_vector_type(8)));
typedef float f32x4 __attribute__((ext_vector_type(4)));
typedef u16 u16x8 __attribute__((ext_vector_type(8)));
typedef u16 u16x4 __attribute__((ext_vector_type(4)));

constexpr int T_SEQ = 2048;
constexpr int HID   = 4096;
constexpr int NH    = 32;
constexpr int NKV   = 8;
constexpr int HD    = 128;
constexpr int QKVN  = 6144;   // 32*128 + 2*8*128

__device__ __forceinline__ u16 f2b(float x) {
  return __builtin_bit_cast(u16, __float2bfloat16(x));
}
__device__ __forceinline__ float b2f(u16 u) {
  return __builtin_bit_cast(float, (unsigned int)u << 16);
}
__device__ __forceinline__ bf16x8 load8(const u16* p) {
  return __builtin_bit_cast(bf16x8, *reinterpret_cast<const u16x8*>(p));
}
__device__ __forceinline__ f32x4 mfma16(bf16x8 a, bf16x8 b, f32x4 c) {
  return __builtin_amdgcn_mfma_f32_16x16x32_bf16(a, b, c, 0, 0, 0);
}
__device__ __forceinline__ void gload_lds16(const u16* src, u16* dst) {
  __builtin_amdgcn_global_load_lds((const __attribute__((address_space(1))) void*)src,
                                   (__attribute__((address_space(3))) void*)dst, 16, 0, 0);
}
#define BAR() asm volatile("s_barrier" ::: "memory")

// ---------------- cast fp32 -> bf16 (vectorized) ----------------
__global__ __launch_bounds__(256) void k_cast_bf16(const float* __restrict__ in,
                                                   u16* __restrict__ out, int n4) {
  int i = blockIdx.x * 256 + threadIdx.x;
  if (i < n4) {
    float4 v = reinterpret_cast<const float4*>(in)[i];
    u16x4 o;
    o.x = f2b(v.x); o.y = f2b(v.y); o.z = f2b(v.z); o.w = f2b(v.w);
    reinterpret_cast<u16x4*>(out)[i] = o;
  }
}

// ---------------- transpose + cast: in[R][C] fp32 -> out[C][R] bf16 ----------------
__global__ __launch_bounds__(256) void k_transpose_cast(const float* __restrict__ in,
                                                        u16* __restrict__ out,
                                                        int R, int C) {
  __shared__ float tile[32][33];
  int cc = blockIdx.x << 5, rr = blockIdx.y << 5;
  int lx = threadIdx.x & 31, ly = threadIdx.x >> 5;
#pragma unroll
  for (int i = 0; i < 32; i += 8)
    tile[ly + i][lx] = in[(size_t)(rr + ly + i) * C + cc + lx];
  __syncthreads();
#pragma unroll
  for (int i = 0; i < 32; i += 8)
    out[(size_t)(cc + ly + i) * R + rr + lx] = f2b(tile[lx][ly + i]);
}

// ---------------- bf16 GEMM, 256x256 8-phase: C[M][N] = A[M][K] * B[N][K]^T ----------------
// 512 thr / 8 waves (2M x 4N), BK=64, LDS 128 KiB double-buffered.
// Swizzle: 16B-slot ^= (row&7), inverse-applied on global source (gload_lds dest linear),
// applied on ds_read. Counted vmcnt(2) once per K-tile; raw s_barrier (no vmcnt0 drain).
// Schedule invariants (verified): stage-lead 5 half-tiles; all 4 halves of tile t complete
// before its P0 reads; every LDS overwrite >=1 barrier after last read of old data.
template <int N, int K, typename OutT>
__global__ __launch_bounds__(512, 2) void k_gemm8(const u16* __restrict__ A,
                                                  const u16* __restrict__ B,
                                                  OutT* __restrict__ C) {
  __shared__ u16 sA[2][256 * 64];
  __shared__ u16 sB[2][256 * 64];
  const int tid = threadIdx.x;
  const int wid = tid >> 6, lane = tid & 63;
  const int g = lane >> 4, c = lane & 15;
  const int wm = wid >> 2, wn = wid & 3;

  // XCD-aware block swizzle (grid % 8 == 0 for both instantiations)
  const int NWG = (T_SEQ / 256) * (N / 256);
  const int wg = (blockIdx.x & 7) * (NWG / 8) + (blockIdx.x >> 3);
  const int NBc = N / 256;
  const int row0 = (wg / NBc) * 256, col0 = (wg % NBc) * 256;
  const int NT = K / 64;

  // stage half-tile h = 4*T + k; k: 0=A-half0, 1=A-half1, 2=B-half0, 3=B-half1
  auto stage_half = [&](int h) {
    const int T = h >> 2, k = h & 3;
    const int buf = T & 1;
    const int kk = T * 64;
    const u16* gbase = (k < 2) ? A : B;
    const int grow0 = ((k < 2) ? row0 : col0) + (k & 1) * 128;
    u16* lbase = ((k < 2) ? sA[buf] : sB[buf]) + (k & 1) * (128 * 64);
#pragma unroll
    for (int i = 0; i < 2; ++i) {
      int L = i * 512 + tid;            // 0..1023 within half-tile
      int r = L >> 3, seg = L & 7;
      const u16* src = gbase + (size_t)(grow0 + r) * K + kk + ((seg ^ (r & 7)) * 8);
      u16* dst = lbase + (i * 512 + wid * 64) * 8;   // wave-uniform; HW adds lane*16B
      gload_lds16(src, dst);
    }
  };

  f32x4 acc[8][4] = {};
  bf16x8 a[4][2], b[4][2];

  auto read_a = [&](int buf, int mbase) {
#pragma unroll
    for (int m = 0; m < 4; ++m) {
      int r = wm * 128 + (mbase + m) * 16 + c;
#pragma unroll
      for (int k2 = 0; k2 < 2; ++k2) {
        int q = k2 * 4 + g;
        a[m][k2] = load8(sA[buf] + r * 64 + ((q ^ (r & 7)) * 8));
      }
    }
  };
  auto read_b = [&](int buf, int nbase) {
#pragma unroll
    for (int n = 0; n < 2; ++n) {
      int r = wn * 64 + (nbase + n) * 16 + c;
#pragma unroll
      for (int k2 = 0; k2 < 2; ++k2) {
        int q = k2 * 4 + g;
        b[nbase + n][k2] = load8(sB[buf] + r * 64 + ((q ^ (r & 7)) * 8));
      }
    }
  };
  auto quad = [&](int mb, int nb) {
    __builtin_amdgcn_s_setprio(1);
#pragma unroll
    for (int m = 0; m < 4; ++m)
#pragma unroll
      for (int n = 0; n < 2; ++n)
#pragma unroll
        for (int k2 = 0; k2 < 2; ++k2)
          acc[mb + m][nb + n] = mfma16(a[m][k2], b[nb + n][k2], acc[mb + m][nb + n]);
    __builtin_amdgcn_s_setprio(0);
  };

  // prologue: stage halves 0..4 (tile0 complete + A0 of tile1), keep half4 in flight
  stage_half(0); stage_half(1); stage_half(2); stage_half(3); stage_half(4);
  asm volatile("s_waitcnt vmcnt(2)" ::: "memory");
  BAR();

  for (int kt = 0; kt < NT; ++kt) {
    const int buf = kt & 1;
    // P0: read A[m0-3] + B[n0-1]; stage A-half1 of kt+1
    read_a(buf, 0); read_b(buf, 0);
    if (4 * kt + 5 < 4 * NT) stage_half(4 * kt + 5);
    BAR();
    quad(0, 0);
    BAR();
    // P1: read B[n2-3]; stage B-half0 of kt+1
    read_b(buf, 2);
    if (4 * kt + 6 < 4 * NT) stage_half(4 * kt + 6);
    BAR();
    quad(0, 2);
    BAR();
    // P2: read A[m4-7]; stage B-half1 of kt+1
    read_a(buf, 4);
    if (4 * kt + 7 < 4 * NT) stage_half(4 * kt + 7);
    BAR();
    quad(4, 0);
    BAR();
    // P3: stage A-half0 of kt+2; counted vmcnt -> tile kt+1 fully resident
    if (4 * kt + 8 < 4 * NT) stage_half(4 * kt + 8);
    asm volatile("s_waitcnt vmcnt(2)" ::: "memory");
    BAR();
    quad(4, 2);
    BAR();
  }

  // epilogue: D layout col=lane&15, row=(lane>>4)*4+reg (m89-verified)
#pragma unroll
  for (int m = 0; m < 8; ++m) {
    int grow0 = row0 + wm * 128 + m * 16 + g * 4;
#pragma unroll
    for (int n = 0; n < 4; ++n) {
      int gcol = col0 + wn * 64 + n * 16 + c;
#pragma unroll
      for (int j = 0; j < 4; ++j) {
        float v = acc[m][n][j];
        if constexpr (sizeof(OutT) == 2)
          C[(size_t)(grow0 + j) * N + gcol] = f2b(v);
        else
          C[(size_t)(grow0 + j) * N + gcol] = v;
      }
    }
  }
}

// ---------------- fused per-head RMSNorm + RoPE + scale, qkv split ----------------
__global__ __launch_bounds__(256) void k_normrope(const u16* __restrict__ qkv,
                                                  const int* __restrict__ pos,
                                                  const float* __restrict__ qw,
                                                  const float* __restrict__ kw,
                                                  u16* __restrict__ qo,
                                                  u16* __restrict__ ko,
                                                  u16* __restrict__ vo) {
  int t = blockIdx.x;
  int wid = threadIdx.x >> 6, lane = threadIdx.x & 63;
  int h = blockIdx.y * 4 + wid;  // 0..47
  const u16* src = qkv + (size_t)t * QKVN + h * HD;
  float x1 = b2f(src[lane]), x2 = b2f(src[lane + 64]);
  float ss = x1 * x1 + x2 * x2;
#pragma unroll
  for (int m = 1; m < 64; m <<= 1) ss += __shfl_xor(ss, m);
  float sc = rsqrtf(ss * (1.0f / HD) + 1e-6f);
  if (h < 40) {
    const float* w = (h < NH) ? qw : kw;
    float y1 = x1 * sc * w[lane], y2 = x2 * sc * w[lane + 64];
    float p = (float)pos[t];
    float inv = exp2f((float)lane * (-13.287712379549449f / 64.0f));
    float ang = p * inv;
    float sn, cs;
    sincosf(ang, &sn, &cs);
    float o1 = y1 * cs - y2 * sn;
    float o2 = y2 * cs + y1 * sn;
    if (h < NH) {
      o1 *= 0.08838834764831845f;  // fold 1/sqrt(128) into q
      o2 *= 0.08838834764831845f;
      u16* dst = qo + ((size_t)t * NH + h) * HD;
      dst[lane] = f2b(o1);
      dst[lane + 64] = f2b(o2);
    } else {
      u16* dst = ko + ((size_t)t * NKV + (h - NH)) * HD;
      dst[lane] = f2b(o1);
      dst[lane + 64] = f2b(o2);
    }
  } else {
    u16* dst = vo + ((size_t)t * NKV + (h - 40)) * HD;
    dst[lane] = f2b(x1);
    dst[lane + 64] = f2b(x2);
  }
}

// ---------------- V transpose: vb[T][NKV][HD] -> vt[NKV][HD][T] ----------------
__global__ __launch_bounds__(256) void k_transpose_v(const u16* __restrict__ vb,
                                                     u16* __restrict__ vt) {
  __shared__ u16 tile[32][33];
  int tt = blockIdx.x << 5, dd = blockIdx.y << 5, h = blockIdx.z;
  int lx = threadIdx.x & 31, ly = threadIdx.x >> 5;
#pragma unroll
  for (int i = 0; i < 32; i += 8)
    tile[ly + i][lx] = vb[((size_t)(tt + ly + i) * NKV + h) * HD + dd + lx];
  __syncthreads();
#pragma unroll
  for (int i = 0; i < 32; i += 8)
    vt[((size_t)h * HD + dd + ly + i) * T_SEQ + tt + lx] = tile[lx][ly + i];
}

// ---------------- flash attention v3: LDS-staged K/V, swapped QK^T softmax ----------------
__global__ __launch_bounds__(256) void k_attn(const u16* __restrict__ qb,
                                              const u16* __restrict__ kbg,
                                              const u16* __restrict__ vtg,
                                              u16* __restrict__ out) {
  __shared__ u16 sK[2][64 * 128];   // [kv 64][hd 128], swz slot^(row&15)
  __shared__ u16 sV[2][128 * 64];   // [d 128][kv 64], swz slot^(d&7)
  const int wid = threadIdx.x >> 6, lane = threadIdx.x & 63;
  const int h = blockIdx.y, hk = h >> 2;
  const int qt = gridDim.x - 1 - blockIdx.x;   // longest blocks launch first
  const int ntiles = qt + 1;
  const int qb0 = qt * 64 + wid * 16;
  const int g = lane >> 4, c = lane & 15;

  auto stage = [&](int buf, int kvb) {
#pragma unroll
    for (int ii = 0; ii < 4; ++ii) {
      int i = wid * 4 + ii;
      {  // K
        int r = i * 4 + (lane >> 4);
        int slot = lane & 15;
        const u16* src = kbg + ((size_t)(kvb + r) * NKV + hk) * HD + ((slot ^ (r & 15)) * 8);
        gload_lds16(src, (u16*)((char*)sK[buf] + i * 1024));
      }
      {  // V
        int d = i * 8 + (lane >> 3);
        int slot3 = lane & 7;
        const u16* src = vtg + ((size_t)hk * HD + d) * T_SEQ + kvb + ((slot3 ^ (d & 7)) * 8);
        gload_lds16(src, (u16*)((char*)sV[buf] + i * 1024));
      }
    }
  };

  bf16x8 qf[4];
  const u16* qrow = qb + ((size_t)(qb0 + c) * NH + h) * HD;
#pragma unroll
  for (int kc = 0; kc < 4; ++kc) qf[kc] = load8(qrow + kc * 32 + g * 8);

  f32x4 accO[8] = {};           // accO[c2][j] = O[q=qb0+4g+j][d=c2*16+c]
  float m_ = -1e30f, l_ = 0.f;  // running max/sum for q = qb0 + c
  const int tq = qb0 + c;

  const int gh = g >> 1, gl4 = 4 * (g & 1), cx = c & 7;
  const int e0 = ((0 + gh) ^ cx) * 8 + gl4;
  const int e1 = ((2 + gh) ^ cx) * 8 + gl4;
  const int e2 = ((4 + gh) ^ cx) * 8 + gl4;
  const int e3 = ((6 + gh) ^ cx) * 8 + gl4;

  stage(0, 0);
  __syncthreads();

  for (int kt = 0; kt < ntiles; ++kt) {
    const int kvb = kt * 64;
    const int cur = kt & 1;
    if (kt + 1 < ntiles) stage(cur ^ 1, kvb + 64);

    f32x4 s[4];
#pragma unroll
    for (int tt = 0; tt < 4; ++tt) {
      const u16* kr = sK[cur] + (tt * 16 + c) * 128;
      f32x4 st = {0.f, 0.f, 0.f, 0.f};
#pragma unroll
      for (int kc = 0; kc < 4; ++kc) {
        int slot = (kc * 4 + g) ^ c;
        st = mfma16(load8(kr + slot * 8), qf[kc], st);
      }
      s[tt] = st;
    }

    float vmax = -1e30f;
#pragma unroll
    for (int tt = 0; tt < 4; ++tt)
#pragma unroll
      for (int j = 0; j < 4; ++j) {
        int tk = kvb + tt * 16 + 4 * g + j;
        float v = (tk <= tq) ? s[tt][j] : -1e30f;
        s[tt][j] = v;
        vmax = fmaxf(vmax, v);
      }
    vmax = fmaxf(vmax, __shfl_xor(vmax, 16));
    vmax = fmaxf(vmax, __shfl_xor(vmax, 32));
    float mn = fmaxf(m_, vmax);
    float a = __expf(m_ - mn);
    float ps = 0.f;
#pragma unroll
    for (int tt = 0; tt < 4; ++tt)
#pragma unroll
      for (int j = 0; j < 4; ++j) {
        float p = __expf(s[tt][j] - mn);
        s[tt][j] = p;
        ps += p;
      }
    ps += __shfl_xor(ps, 16);
    ps += __shfl_xor(ps, 32);
    l_ = l_ * a + ps;
    m_ = mn;

    float aq[4];
#pragma unroll
    for (int j = 0; j < 4; ++j) aq[j] = __shfl(a, 20 * g + j);
#pragma unroll
    for (int c2 = 0; c2 < 8; ++c2)
#pragma unroll
      for (int j = 0; j < 4; ++j) accO[c2][j] *= aq[j];

    u16x8 p0u, p1u;
#pragma unroll
    for (int j = 0; j < 4; ++j) {
      p0u[j]     = f2b(s[0][j]);
      p0u[j + 4] = f2b(s[1][j]);
      p1u[j]     = f2b(s[2][j]);
      p1u[j + 4] = f2b(s[3][j]);
    }
    bf16x8 p0 = __builtin_bit_cast(bf16x8, p0u);
    bf16x8 p1 = __builtin_bit_cast(bf16x8, p1u);

#pragma unroll
    for (int c2 = 0; c2 < 8; ++c2) {
      const u16* vr = sV[cur] + (c2 * 16 + c) * 64;
      u16x4 va  = *reinterpret_cast<const u16x4*>(vr + e0);
      u16x4 vb4 = *reinterpret_cast<const u16x4*>(vr + e1);
      u16x4 vc4 = *reinterpret_cast<const u16x4*>(vr + e2);
      u16x4 vd  = *reinterpret_cast<const u16x4*>(vr + e3);
      u16x8 v0u, v1u;
#pragma unroll
      for (int j = 0; j < 4; ++j) {
        v0u[j] = va[j];  v0u[j + 4] = vb4[j];
        v1u[j] = vc4[j]; v1u[j + 4] = vd[j];
      }
      accO[c2] = mfma16(p0, __builtin_bit_cast(bf16x8, v0u), accO[c2]);
      accO[c2] = mfma16(p1, __builtin_bit_cast(bf16x8, v1u), accO[c2]);
    }

    __syncthreads();
  }

  float lq[4];
#pragma unroll
  for (int j = 0; j < 4; ++j) lq[j] = 1.0f / __shfl(l_, 20 * g + j);
#pragma unroll
  for (int c2 = 0; c2 < 8; ++c2)
#pragma unroll
    for (int j = 0; j < 4; ++j) {
      float o = accO[c2][j] * lq[j];
      out[(size_t)(qb0 + 4 * g + j) * HID + h * HD + c2 * 16 + c] = f2b(o);
    }
}

// ---------------- launch ----------------
extern "C" void kernel_launch(void* const* d_in, const int* in_sizes, int n_in,
                              void* d_out, int out_size, void* d_ws, size_t ws_size,
                              hipStream_t stream) {
  (void)in_sizes; (void)n_in; (void)out_size; (void)ws_size;
  const float* x      = (const float*)d_in[0];
  const int*   pos    = (const int*)d_in[1];
  const float* qkv_w  = (const float*)d_in[2];
  const float* qnw    = (const float*)d_in[3];
  const float* knw    = (const float*)d_in[4];
  const float* ow     = (const float*)d_in[5];
  float* out = (float*)d_out;
  char* ws = (char*)d_ws;

  // region A (16,777,216 B): xb then attn
  u16* xb   = (u16*)(ws + 0);
  u16* attn = (u16*)(ws + 0);
  // region B (50,331,648 B): qkv_wt then {qb, kb, vb, vt}
  char* B0 = ws + 16777216;
  u16* qkv_wt = (u16*)B0;
  u16* qbuf = (u16*)(B0 + 0);
  u16* kbuf = (u16*)(B0 + 16777216);
  u16* vbuf = (u16*)(B0 + 20971520);
  u16* vtb  = (u16*)(B0 + 25165824);
  // region C (33,554,432 B): qkv bf16 then o_wt
  char* C0 = ws + 67108864;
  u16* qkvb = (u16*)C0;
  u16* o_wt = (u16*)C0;

  // 1. cast x -> bf16
  k_cast_bf16<<<dim3((T_SEQ * HID / 4 + 255) / 256), 256, 0, stream>>>(x, xb, T_SEQ * HID / 4);
  // 2. transpose-cast qkv_w [4096][6144] -> [6144][4096] bf16
  k_transpose_cast<<<dim3(QKVN / 32, HID / 32), 256, 0, stream>>>(qkv_w, qkv_wt, HID, QKVN);
  // 3. qkv GEMM -> bf16 [T][6144]  (192 blocks, 8-phase 256^2)
  k_gemm8<QKVN, HID, u16><<<dim3((T_SEQ / 256) * (QKVN / 256)), 512, 0, stream>>>(xb, qkv_wt, qkvb);
  // 4. rmsnorm + rope + split (overwrites region B; qkv_wt dead)
  k_normrope<<<dim3(T_SEQ, 12), 256, 0, stream>>>(qkvb, pos, qnw, knw, qbuf, kbuf, vbuf);
  // 5. V transpose [T][8][128] -> [8][128][T]
  k_transpose_v<<<dim3(T_SEQ / 32, HD / 32, NKV), 256, 0, stream>>>(vbuf, vtb);
  // 6. transpose-cast o_w -> [N][K] bf16 (overwrites region C; qkvb dead)
  k_transpose_cast<<<dim3(HID / 32, HID / 32), 256, 0, stream>>>(ow, o_wt, HID, HID);
  // 7. attention -> attn bf16 [T][4096] (overwrites region A; xb dead)
  k_attn<<<dim3(T_SEQ / 64, NH), 256, 0, stream>>>(qbuf, kbuf, vtb, attn);
  // 8. output GEMM -> fp32 d_out  (128 blocks, 8-phase 256^2)
  k_gemm8<HID, HID, float><<<dim3((T_SEQ / 256) * (HID / 256)), 512, 0, stream>>>(attn, o_wt, out);
}